// Round 14
// baseline (83.759 us; speedup 1.0000x reference)
//
#include <hip/hip_runtime.h>
#include <math.h>

// Problem constants (from reference setup_inputs)
static constexpr int N_ = 4, R_ = 256, C_ = 1024, H_ = 50, W_ = 50, P_ = 7;
static constexpr int HW_ = H_ * W_;            // 2500 words per plane
static constexpr int PP_ = P_ * P_;            // 49 output pixels per (roi, channel)
static constexpr int CHB_ = 4;                 // channels (planes) per block
static constexpr int WVS_ = 16;                // waves per block (1024 threads)
static constexpr int RS_ = 84;                 // jittered LDS row stride (words)
static constexpr int PLW_ = 4352;              // LDS plane words (17 x 256, staged)
static constexpr int FM_WORDS = N_ * C_ * HW_; // 10,240,000

typedef const __attribute__((address_space(1))) void* gaddr_t;
typedef __attribute__((address_space(3))) void* laddr_t;

__device__ __forceinline__ void ld_lds16(const float* g, float* l) {
    // async global->LDS DMA, 16B/lane; dest = wave-uniform base + lane*16B
    __builtin_amdgcn_global_load_lds((gaddr_t)g, (laddr_t)l, 16, 0, 0);
}

// Non-linear row jitter: T(r) = r(r+1)/2 mod 32. Row r of a plane lives at
// LDS words [RS_*r + T(r), +50). Linear strides can't break the bank lattice
// (S*dr + dc == 0 mod 32 always has solutions inside a 13x13 window); the
// varying delta of T(r) can. LDS layout == global layout with per-row shifts,
// and the global plane is contiguous -> DMA source = gpb + (w - 34r - T(r)).
__device__ __forceinline__ int jit(int r) { return ((r * (r + 1)) >> 1) & 31; }

// Per-axis geometry, ABSOLUTE indices. rois >= 0 => i0 >= 0 (no left clamp).
// Zero-padding validity folded into weights; i0 clamped <= L-1.
// A-sub-sample corners span rows/cols {0,1} only (wA[2] == 0 -> pruned).
__device__ __forceinline__ void axis_w(float p0, float p1, int L,
                                       int& i0c, float wA[2], float wB[3]) {
    float f0 = floorf(p0); int i0 = (int)f0; float a0 = p0 - f0;
    float f1 = floorf(p1); int i1 = (int)f1; float a1 = p1 - f1;
    const bool o = (i1 > i0);
    wA[0] = 1.0f - a0; wA[1] = a0;
    wB[0] = o ? 0.0f : (1.0f - a1);
    wB[1] = o ? (1.0f - a1) : a1;
    wB[2] = o ? a1 : 0.0f;
    if (i0 > L - 1)     { wA[0] = 0.0f; wB[0] = 0.0f; }
    if (i0 + 1 > L - 1) { wA[1] = 0.0f; wB[1] = 0.0f; }
    if (i0 + 2 > L - 1) {               wB[2] = 0.0f; }
    i0c = min(max(i0, 0), L - 1);
}

// 9 reads from 3 per-row bases; {0,1} pairs merge into ds_read2_b32.
// Pruned reduce: 25 VALU ops/channel.
__device__ __forceinline__ float gather9(const float* __restrict__ g0,
                                         const float* __restrict__ g1,
                                         const float* __restrict__ g2,
                                         const float wyA[2], const float wyB[3],
                                         const float wxA[2], const float wxB[3]) {
    const float v00 = g0[0], v01 = g0[1], v02 = g0[2];
    const float v10 = g1[0], v11 = g1[1], v12 = g1[2];
    const float v20 = g2[0], v21 = g2[1], v22 = g2[2];

    const float tA0 = fmaf(wyA[1], v10, wyA[0] * v00);
    const float tA1 = fmaf(wyA[1], v11, wyA[0] * v01);
    const float tA2 = fmaf(wyA[1], v12, wyA[0] * v02);
    const float tB0 = fmaf(wyB[2], v20, fmaf(wyB[1], v10, wyB[0] * v00));
    const float tB1 = fmaf(wyB[2], v21, fmaf(wyB[1], v11, wyB[0] * v01));
    const float tB2 = fmaf(wyB[2], v22, fmaf(wyB[1], v12, wyB[0] * v02));

    const float s00 = fmaf(wxA[1], tA1, wxA[0] * tA0);
    const float s01 = fmaf(wxB[2], tA2, fmaf(wxB[1], tA1, wxB[0] * tA0));
    const float s10 = fmaf(wxA[1], tB1, wxA[0] * tB0);
    const float s11 = fmaf(wxB[2], tB2, fmaf(wxB[1], tB1, wxB[0] * tB0));

    return fmaxf(fmaxf(s00, s01), fmaxf(s10, s11));
}

// PLANE-RESIDENT, 16 waves: block = (image n, 4 channels). Waves cooperatively
// stage 4 jitter-laid-out planes (wave w: plane w>>2, chunk quarter w&3), then
// serve all 256 ROIs (wave w -> rois w, w+16, ...; lane = output pixel).
// 69.6KB LDS -> 2 blocks/CU = 32 waves/CU (8/SIMD).
__global__ __launch_bounds__(1024) void roipool_kernel(
    const float* __restrict__ rois,
    const float* __restrict__ fm,
    float* __restrict__ out) {

    __shared__ float planes[CHB_][PLW_];      // 69.6 KB

    const int b  = blockIdx.x;                // grid = N_ * 256
    const int n  = b >> 8;
    const int c0 = (b & 255) * CHB_;
    const int lane = threadIdx.x & 63;
    const int wv = __builtin_amdgcn_readfirstlane(threadIdx.x >> 6);

    // ---- stage: wave w covers plane w>>2, chunk rounds 5*(w&3)..min(+5,17).
    // LDS word w -> row r = w/RS_, source word = w - 34r - T(r) within the
    // contiguous global plane (straddle chunks pull neighbor-row data, which
    // is exactly correct for real cols and harmless for never-read words).
    {
        const int pl = wv >> 2;
        const int qh = wv & 3;
        const int gpb = (n * C_ + c0 + pl) * HW_;
        float* dst = &planes[pl][0];
        const int t0 = qh * 5, t1 = min(t0 + 5, 17);
        for (int t = t0; t < t1; ++t) {
            const int w = t * 256 + lane * 4;
            const int r = w / RS_;                       // const-div, 0..51
            const int src = gpb + w - 34 * r - jit(r);   // >= 0 (T(0)=0)
            ld_lds16(fm + min(src, FM_WORDS - 4), dst + w);
        }
    }
    asm volatile("s_waitcnt vmcnt(0)" ::: "memory");
    __syncthreads();

    int pi = lane / 7;
    int pj = lane - pi * 7;
    const bool active = lane < PP_;
    if (!active) { pi = 0; pj = 0; }          // idle lanes mirror lane 0

    const size_t obase = ((size_t)n * R_ * C_ + c0) * PP_ + lane;

    for (int r = wv; r < R_; r += WVS_) {
        const float4 roi = reinterpret_cast<const float4*>(rois)[n * R_ + r];
        const float y1 = roi.x * 0.0625f;
        const float x1 = roi.y * 0.0625f;
        const float y2 = (roi.x + roi.z) * 0.0625f;
        const float x2 = (roi.y + roi.w) * 0.0625f;
        const float sy = (y2 - y1) * (1.0f / 13.0f);
        const float sx = (x2 - x1) * (1.0f / 13.0f);

        const float py0 = y1 + sy * (float)(2 * pi);
        const float py1 = y1 + sy * (float)(2 * pi + 1);
        const float px0 = x1 + sx * (float)(2 * pj);
        const float px1 = x1 + sx * (float)(2 * pj + 1);

        int iy0; float wyA[2], wyB[3];
        axis_w(py0, py1, H_, iy0, wyA, wyB);
        int ix0; float wxA[2], wxB[3];
        axis_w(px0, px1, W_, ix0, wxA, wxB);

        // 3 jittered row bases (rows clamped; clamped rows carry zero weight).
        const int ry1 = min(iy0 + 1, H_ - 1);
        const int ry2 = min(iy0 + 2, H_ - 1);
        const int gb0 = RS_ * iy0 + jit(iy0) + ix0;   // <= 84*49+31+49 = 4196
        const int gb1 = RS_ * ry1 + jit(ry1) + ix0;
        const int gb2 = RS_ * ry2 + jit(ry2) + ix0;   // reads +2 <= 4198 < 4352

        float r0, r1, r2, r3;
        {
            const float* p = &planes[0][0];
            r0 = gather9(p + gb0, p + gb1, p + gb2, wyA, wyB, wxA, wxB);
        }
        {
            const float* p = &planes[1][0];
            r1 = gather9(p + gb0, p + gb1, p + gb2, wyA, wyB, wxA, wxB);
        }
        {
            const float* p = &planes[2][0];
            r2 = gather9(p + gb0, p + gb1, p + gb2, wyA, wyB, wxA, wxB);
        }
        {
            const float* p = &planes[3][0];
            r3 = gather9(p + gb0, p + gb1, p + gb2, wyA, wyB, wxA, wxB);
        }

        if (active) {
            float* __restrict__ po = out + obase + (size_t)r * C_ * PP_;
            po[0]       = r0;
            po[PP_]     = r1;
            po[2 * PP_] = r2;
            po[3 * PP_] = r3;
        }
    }
}

extern "C" void kernel_launch(void* const* d_in, const int* in_sizes, int n_in,
                              void* d_out, int out_size, void* d_ws, size_t ws_size,
                              hipStream_t stream) {
    const float* rois = (const float*)d_in[0];        // [4,256,4]
    const float* fm   = (const float*)d_in[1];        // [4,1024,50,50]
    float* out        = (float*)d_out;                // [4,256,1024,7,7]

    const int blocks = N_ * (C_ / CHB_);              // 4 * 256 = 1024
    roipool_kernel<<<blocks, 1024, 0, stream>>>(rois, fm, out);
}

// Round 15
// 77.853 us; speedup vs baseline: 1.0759x; 1.0759x over previous
//
#include <hip/hip_runtime.h>
#include <math.h>

// Problem constants (from reference setup_inputs)
static constexpr int N_ = 4, R_ = 256, C_ = 1024, H_ = 50, W_ = 50, P_ = 7;
static constexpr int HW_ = H_ * W_;            // 2500 words per plane
static constexpr int PP_ = P_ * P_;            // 49 output pixels per (roi, channel)
static constexpr int CHB_ = 4;                 // channels (planes) per block
static constexpr int WVS_ = 16;                // waves per block (1024 threads)
static constexpr int PLW_ = 2816;              // LDS plane stride (11*256 staged)
static constexpr int NTASK = R_ * PP_;         // 12544 = 64 * 196 exactly
static constexpr int NIT = NTASK / 64;         // 196 wave-iterations per block
static constexpr int FM_WORDS = N_ * C_ * HW_; // 10,240,000

typedef const __attribute__((address_space(1))) void* gaddr_t;
typedef __attribute__((address_space(3))) void* laddr_t;

__device__ __forceinline__ void ld_lds16(const float* g, float* l) {
    // async global->LDS DMA, 16B/lane; dest = wave-uniform base + lane*16B
    __builtin_amdgcn_global_load_lds((gaddr_t)g, (laddr_t)l, 16, 0, 0);
}

// Per-axis geometry, ABSOLUTE indices. rois >= 0 => i0 >= 0 (no left clamp).
// Zero-padding validity folded into weights; i0 clamped <= L-1 so LDS reads
// stay <= 2499+102 < 2816 (all staged, finite).
// A-sub-sample corners span rows/cols {0,1} only (wA[2] == 0 -> pruned).
__device__ __forceinline__ void axis_w(float p0, float p1, int L,
                                       int& i0c, float wA[2], float wB[3]) {
    float f0 = floorf(p0); int i0 = (int)f0; float a0 = p0 - f0;
    float f1 = floorf(p1); int i1 = (int)f1; float a1 = p1 - f1;
    const bool o = (i1 > i0);
    wA[0] = 1.0f - a0; wA[1] = a0;
    wB[0] = o ? 0.0f : (1.0f - a1);
    wB[1] = o ? (1.0f - a1) : a1;
    wB[2] = o ? a1 : 0.0f;
    if (i0 > L - 1)     { wA[0] = 0.0f; wB[0] = 0.0f; }
    if (i0 + 1 > L - 1) { wA[1] = 0.0f; wB[1] = 0.0f; }
    if (i0 + 2 > L - 1) {               wB[2] = 0.0f; }
    i0c = min(max(i0, 0), L - 1);
}

// 9 LDS reads at compile-time offsets {0,1,2,50,51,52,100,101,102} from one
// per-lane base -> LLVM merges const-offset pairs into ds_read2_b32.
// Pruned reduce: 25 VALU ops/channel.
__device__ __forceinline__ float gather9(const float* __restrict__ g,
                                         const float wyA[2], const float wyB[3],
                                         const float wxA[2], const float wxB[3]) {
    const float v00 = g[0],       v01 = g[1],          v02 = g[2];
    const float v10 = g[W_],      v11 = g[W_ + 1],     v12 = g[W_ + 2];
    const float v20 = g[2 * W_],  v21 = g[2 * W_ + 1], v22 = g[2 * W_ + 2];

    const float tA0 = fmaf(wyA[1], v10, wyA[0] * v00);
    const float tA1 = fmaf(wyA[1], v11, wyA[0] * v01);
    const float tA2 = fmaf(wyA[1], v12, wyA[0] * v02);
    const float tB0 = fmaf(wyB[2], v20, fmaf(wyB[1], v10, wyB[0] * v00));
    const float tB1 = fmaf(wyB[2], v21, fmaf(wyB[1], v11, wyB[0] * v01));
    const float tB2 = fmaf(wyB[2], v22, fmaf(wyB[1], v12, wyB[0] * v02));

    const float s00 = fmaf(wxA[1], tA1, wxA[0] * tA0);
    const float s01 = fmaf(wxB[2], tA2, fmaf(wxB[1], tA1, wxB[0] * tA0));
    const float s10 = fmaf(wxA[1], tB1, wxA[0] * tB0);
    const float s11 = fmaf(wxB[2], tB2, fmaf(wxB[1], tB1, wxB[0] * tB0));

    return fmaxf(fmaxf(s00, s01), fmaxf(s10, s11));
}

// PLANE-RESIDENT + FLAT TASK PACKING, 16 waves: block = (image n, 4 channels).
// Stage the 4 planes once, then run 256 rois x 49 pixels as a FLAT stream of
// 12544 tasks = 196 full-wave iterations: every lane productive every instr
// (was 49/64), no exec masking, no tail. Lane decodes (roi, pixel) by magic
// division; roi float4 comes from the L1-resident 4KB table (lanes in a wave
// share 1-2 rois). Geometry amortizes over the 4 channels as before.
__global__ __launch_bounds__(1024) void roipool_kernel(
    const float* __restrict__ rois,
    const float* __restrict__ fm,
    float* __restrict__ out) {

    __shared__ float planes[CHB_][PLW_];      // 45 KB -> 2 blocks/CU, 8 waves/SIMD

    const int b  = blockIdx.x;                // grid = N_ * 256
    const int n  = b >> 8;
    const int c0 = (b & 255) * CHB_;
    const int lane = threadIdx.x & 63;
    const int wv = __builtin_amdgcn_readfirstlane(threadIdx.x >> 6);

    // ---- stage: wave w covers plane w>>2, chunks 3*(w&3) .. min(+3,11) ----
    {
        const int pl = wv >> 2;
        const int qh = wv & 3;
        const int base = (n * C_ + c0 + pl) * HW_;
        float* dst = &planes[pl][0];
        const int t0 = qh * 3, t1 = min(t0 + 3, 11);
        for (int t = t0; t < t1; ++t) {
            const int src = min(base + t * 256 + lane * 4, FM_WORDS - 4);
            ld_lds16(fm + src, dst + t * 256);
        }
    }
    asm volatile("s_waitcnt vmcnt(0)" ::: "memory");
    __syncthreads();

    const float* const p0l = &planes[0][0];
    const float* const p1l = &planes[1][0];
    const float* const p2l = &planes[2][0];
    const float* const p3l = &planes[3][0];

    const float4* __restrict__ rois4 = reinterpret_cast<const float4*>(rois) + n * R_;
    const size_t obase = ((size_t)n * R_ * C_ + c0) * PP_;

    for (int it = wv; it < NIT; it += WVS_) {
        const int t  = (it << 6) | lane;                 // 0 .. 12543
        const int ri = (int)((unsigned)t / 49u);         // roi 0..255 (magic mul)
        const int px = t - ri * 49;                      // pixel 0..48
        const int pi = (int)((unsigned)px / 7u);
        const int pj = px - pi * 7;

        const float4 roi = rois4[ri];
        const float y1 = roi.x * 0.0625f;
        const float x1 = roi.y * 0.0625f;
        const float y2 = (roi.x + roi.z) * 0.0625f;
        const float x2 = (roi.y + roi.w) * 0.0625f;
        const float sy = (y2 - y1) * (1.0f / 13.0f);
        const float sx = (x2 - x1) * (1.0f / 13.0f);

        const float py0 = y1 + sy * (float)(2 * pi);
        const float py1 = y1 + sy * (float)(2 * pi + 1);
        const float px0 = x1 + sx * (float)(2 * pj);
        const float px1 = x1 + sx * (float)(2 * pj + 1);

        int iy0; float wyA[2], wyB[3];
        axis_w(py0, py1, H_, iy0, wyA, wyB);
        int ix0; float wxA[2], wxB[3];
        axis_w(px0, px1, W_, ix0, wxA, wxB);
        const int gb = iy0 * W_ + ix0;        // <= 2499; reads reach <= 2601

        const float r0 = gather9(p0l + gb, wyA, wyB, wxA, wxB);
        const float r1 = gather9(p1l + gb, wyA, wyB, wxA, wxB);
        const float r2 = gather9(p2l + gb, wyA, wyB, wxA, wxB);
        const float r3 = gather9(p3l + gb, wyA, wyB, wxA, wxB);

        float* __restrict__ po = out + obase + (size_t)ri * C_ * PP_ + px;
        po[0]       = r0;
        po[PP_]     = r1;
        po[2 * PP_] = r2;
        po[3 * PP_] = r3;
    }
}

extern "C" void kernel_launch(void* const* d_in, const int* in_sizes, int n_in,
                              void* d_out, int out_size, void* d_ws, size_t ws_size,
                              hipStream_t stream) {
    const float* rois = (const float*)d_in[0];        // [4,256,4]
    const float* fm   = (const float*)d_in[1];        // [4,1024,50,50]
    float* out        = (float*)d_out;                // [4,256,1024,7,7]

    const int blocks = N_ * (C_ / CHB_);              // 4 * 256 = 1024
    roipool_kernel<<<blocks, 1024, 0, stream>>>(rois, fm, out);
}

// Round 16
// 77.421 us; speedup vs baseline: 1.0819x; 1.0056x over previous
//
#include <hip/hip_runtime.h>
#include <math.h>

// Problem constants (from reference setup_inputs)
static constexpr int N_ = 4, R_ = 256, C_ = 1024, H_ = 50, W_ = 50, P_ = 7;
static constexpr int HW_ = H_ * W_;            // 2500 words per plane
static constexpr int PP_ = P_ * P_;            // 49 output pixels per (roi, channel)
static constexpr int CHB_ = 4;                 // channels (planes) per block
static constexpr int WVS_ = 16;                // waves per block (1024 threads)
static constexpr int PLW_ = 2816;              // LDS plane stride (11*256 staged)
static constexpr int NTASK = R_ * PP_;         // 12544 = 64 * 196 exactly
static constexpr int NIT = NTASK / 64;         // 196 wave-iterations per block
static constexpr int FM_WORDS = N_ * C_ * HW_; // 10,240,000

typedef const __attribute__((address_space(1))) void* gaddr_t;
typedef __attribute__((address_space(3))) void* laddr_t;

__device__ __forceinline__ void ld_lds16(const float* g, float* l) {
    // async global->LDS DMA, 16B/lane; dest = wave-uniform base + lane*16B
    __builtin_amdgcn_global_load_lds((gaddr_t)g, (laddr_t)l, 16, 0, 0);
}

// Per-axis geometry, ABSOLUTE indices. rois >= 0 => i0 >= 0 (no left clamp).
// Zero-padding validity folded into weights; i0 clamped <= L-1 so LDS reads
// stay <= 2499+102 < 2816 (all staged, finite).
// A-sub-sample corners span rows/cols {0,1} only (wA[2] == 0 -> pruned).
__device__ __forceinline__ void axis_w(float p0, float p1, int L,
                                       int& i0c, float wA[2], float wB[3]) {
    float f0 = floorf(p0); int i0 = (int)f0; float a0 = p0 - f0;
    float f1 = floorf(p1); int i1 = (int)f1; float a1 = p1 - f1;
    const bool o = (i1 > i0);
    wA[0] = 1.0f - a0; wA[1] = a0;
    wB[0] = o ? 0.0f : (1.0f - a1);
    wB[1] = o ? (1.0f - a1) : a1;
    wB[2] = o ? a1 : 0.0f;
    if (i0 > L - 1)     { wA[0] = 0.0f; wB[0] = 0.0f; }
    if (i0 + 1 > L - 1) { wA[1] = 0.0f; wB[1] = 0.0f; }
    if (i0 + 2 > L - 1) {               wB[2] = 0.0f; }
    i0c = min(max(i0, 0), L - 1);
}

// 9 LDS reads at compile-time offsets {0,1,2,50,51,52,100,101,102} from one
// per-lane base -> LLVM merges const-offset pairs into ds_read2_b32.
// Pruned reduce: 25 VALU ops/channel.
__device__ __forceinline__ float gather9(const float* __restrict__ g,
                                         const float wyA[2], const float wyB[3],
                                         const float wxA[2], const float wxB[3]) {
    const float v00 = g[0],       v01 = g[1],          v02 = g[2];
    const float v10 = g[W_],      v11 = g[W_ + 1],     v12 = g[W_ + 2];
    const float v20 = g[2 * W_],  v21 = g[2 * W_ + 1], v22 = g[2 * W_ + 2];

    const float tA0 = fmaf(wyA[1], v10, wyA[0] * v00);
    const float tA1 = fmaf(wyA[1], v11, wyA[0] * v01);
    const float tA2 = fmaf(wyA[1], v12, wyA[0] * v02);
    const float tB0 = fmaf(wyB[2], v20, fmaf(wyB[1], v10, wyB[0] * v00));
    const float tB1 = fmaf(wyB[2], v21, fmaf(wyB[1], v11, wyB[0] * v01));
    const float tB2 = fmaf(wyB[2], v22, fmaf(wyB[1], v12, wyB[0] * v02));

    const float s00 = fmaf(wxA[1], tA1, wxA[0] * tA0);
    const float s01 = fmaf(wxB[2], tA2, fmaf(wxB[1], tA1, wxB[0] * tA0));
    const float s10 = fmaf(wxA[1], tB1, wxA[0] * tB0);
    const float s11 = fmaf(wxB[2], tB2, fmaf(wxB[1], tB1, wxB[0] * tB0));

    return fmaxf(fmaxf(s00, s01), fmaxf(s10, s11));
}

// PLANE-RESIDENT + FLAT TASK PACKING, 16 waves: block = (image n, 4 channels).
// Stage the 4 planes once, then run 256 rois x 49 pixels as a FLAT stream of
// 12544 tasks = 196 full-wave iterations (every lane productive, no tail).
// __launch_bounds__(1024, 8): force VGPR <= 64 so TWO 16-wave blocks fit per
// CU (r13-r15 ran at VGPR=68 -> 1 block/CU = 4 waves/SIMD, half the designed
// occupancy; the kernel is DS-latency-chained, so TLP is the binding lever).
__global__ __launch_bounds__(1024, 8) void roipool_kernel(
    const float* __restrict__ rois,
    const float* __restrict__ fm,
    float* __restrict__ out) {

    __shared__ float planes[CHB_][PLW_];      // 45 KB -> 2 blocks/CU, 8 waves/SIMD

    const int b  = blockIdx.x;                // grid = N_ * 256
    const int n  = b >> 8;
    const int c0 = (b & 255) * CHB_;
    const int lane = threadIdx.x & 63;
    const int wv = __builtin_amdgcn_readfirstlane(threadIdx.x >> 6);

    // ---- stage: wave w covers plane w>>2, chunks 3*(w&3) .. min(+3,11) ----
    {
        const int pl = wv >> 2;
        const int qh = wv & 3;
        const int base = (n * C_ + c0 + pl) * HW_;
        float* dst = &planes[pl][0];
        const int t0 = qh * 3, t1 = min(t0 + 3, 11);
        for (int t = t0; t < t1; ++t) {
            const int src = min(base + t * 256 + lane * 4, FM_WORDS - 4);
            ld_lds16(fm + src, dst + t * 256);
        }
    }
    asm volatile("s_waitcnt vmcnt(0)" ::: "memory");
    __syncthreads();

    const float* const p0l = &planes[0][0];
    const float* const p1l = &planes[1][0];
    const float* const p2l = &planes[2][0];
    const float* const p3l = &planes[3][0];

    const float4* __restrict__ rois4 = reinterpret_cast<const float4*>(rois) + n * R_;
    const size_t obase = ((size_t)n * R_ * C_ + c0) * PP_;

    for (int it = wv; it < NIT; it += WVS_) {
        const int t  = (it << 6) | lane;                 // 0 .. 12543
        const int ri = (int)((unsigned)t / 49u);         // roi 0..255 (magic mul)
        const int px = t - ri * 49;                      // pixel 0..48
        const int pi = (int)((unsigned)px / 7u);
        const int pj = px - pi * 7;

        const float4 roi = rois4[ri];
        const float y1 = roi.x * 0.0625f;
        const float x1 = roi.y * 0.0625f;
        const float y2 = (roi.x + roi.z) * 0.0625f;
        const float x2 = (roi.y + roi.w) * 0.0625f;
        const float sy = (y2 - y1) * (1.0f / 13.0f);
        const float sx = (x2 - x1) * (1.0f / 13.0f);

        const float py0 = y1 + sy * (float)(2 * pi);
        const float py1 = y1 + sy * (float)(2 * pi + 1);
        const float px0 = x1 + sx * (float)(2 * pj);
        const float px1 = x1 + sx * (float)(2 * pj + 1);

        int iy0; float wyA[2], wyB[3];
        axis_w(py0, py1, H_, iy0, wyA, wyB);
        int ix0; float wxA[2], wxB[3];
        axis_w(px0, px1, W_, ix0, wxA, wxB);
        const int gb = iy0 * W_ + ix0;        // <= 2499; reads reach <= 2601

        const float r0 = gather9(p0l + gb, wyA, wyB, wxA, wxB);
        const float r1 = gather9(p1l + gb, wyA, wyB, wxA, wxB);
        const float r2 = gather9(p2l + gb, wyA, wyB, wxA, wxB);
        const float r3 = gather9(p3l + gb, wyA, wyB, wxA, wxB);

        float* __restrict__ po = out + obase + (size_t)ri * C_ * PP_ + px;
        po[0]       = r0;
        po[PP_]     = r1;
        po[2 * PP_] = r2;
        po[3 * PP_] = r3;
    }
}

extern "C" void kernel_launch(void* const* d_in, const int* in_sizes, int n_in,
                              void* d_out, int out_size, void* d_ws, size_t ws_size,
                              hipStream_t stream) {
    const float* rois = (const float*)d_in[0];        // [4,256,4]
    const float* fm   = (const float*)d_in[1];        // [4,1024,50,50]
    float* out        = (float*)d_out;                // [4,256,1024,7,7]

    const int blocks = N_ * (C_ / CHB_);              // 4 * 256 = 1024
    roipool_kernel<<<blocks, 1024, 0, stream>>>(rois, fm, out);
}

// Round 17
// 72.705 us; speedup vs baseline: 1.1520x; 1.0649x over previous
//
#include <hip/hip_runtime.h>
#include <math.h>

// Problem constants (from reference setup_inputs)
static constexpr int N_ = 4, R_ = 256, C_ = 1024, H_ = 50, W_ = 50, P_ = 7;
static constexpr int HW_ = H_ * W_;            // 2500 words per plane
static constexpr int PP_ = P_ * P_;            // 49 output pixels per (roi, channel)
static constexpr int CHB_ = 4;                 // channels per block (float4-interleaved)
static constexpr int WVS_ = 8;                 // waves per block (512 threads)
static constexpr int P4_ = 2608;               // staged float4 slots (reads reach 2601+)
static constexpr int NTASK = R_ * PP_;         // 12544 = 64 * 196 exactly
static constexpr int NIT = NTASK / 64;         // 196 wave-iterations per block

// Per-axis geometry, ABSOLUTE indices. rois >= 0 => i0 >= 0 (no left clamp).
// Zero-padding validity folded into weights; i0 clamped <= L-1 so LDS reads
// stay <= 2499+102 < 2608 (all staged, finite).
// A-sub-sample corners span rows/cols {0,1} only (wA[2] == 0 -> pruned).
__device__ __forceinline__ void axis_w(float p0, float p1, int L,
                                       int& i0c, float wA[2], float wB[3]) {
    float f0 = floorf(p0); int i0 = (int)f0; float a0 = p0 - f0;
    float f1 = floorf(p1); int i1 = (int)f1; float a1 = p1 - f1;
    const bool o = (i1 > i0);
    wA[0] = 1.0f - a0; wA[1] = a0;
    wB[0] = o ? 0.0f : (1.0f - a1);
    wB[1] = o ? (1.0f - a1) : a1;
    wB[2] = o ? a1 : 0.0f;
    if (i0 > L - 1)     { wA[0] = 0.0f; wB[0] = 0.0f; }
    if (i0 + 1 > L - 1) { wA[1] = 0.0f; wB[1] = 0.0f; }
    if (i0 + 2 > L - 1) {               wB[2] = 0.0f; }
    i0c = min(max(i0, 0), L - 1);
}

// CHANNEL-INTERLEAVED PLANE-RESIDENT: block = (image n, 4 channels). LDS holds
// sh4[p] = float4{ch0..ch3}[p] -- every patch position is ONE aligned 16B unit,
// so a 3x3 window gather for ALL 4 channels is 9 x ds_read_b128 (wide-access
// rate ~85 B/cyc, m134) instead of 20 narrow b32/read2 ops (~44 B/cyc). The
// DS pipe is the measured bottleneck (r11-r16 ledger); same bytes, ~2x rate.
__global__ __launch_bounds__(512) void roipool_kernel(
    const float* __restrict__ rois,
    const float* __restrict__ fm,
    float* __restrict__ out) {

    __shared__ float4 sh4[P4_];               // 41.7 KB

    const int b  = blockIdx.x;                // grid = N_ * 256
    const int n  = b >> 8;
    const int c0 = (b & 255) * CHB_;
    const int tid = threadIdx.x;
    const int lane = tid & 63;
    const int wv = __builtin_amdgcn_readfirstlane(tid >> 6);

    // ---- transpose-stage: thread p loads 4 coalesced dwords (one per plane,
    // stride HW_) and writes one aligned float4. p >= HW_ slots get clamped
    // junk (finite, never carries weight).
    {
        const int gpb = (n * C_ + c0) * HW_;
        for (int p = tid; p < P4_; p += 512) {
            const int sp = min(p, HW_ - 1);
            float4 v;
            v.x = fm[gpb + sp];
            v.y = fm[gpb + HW_ + sp];
            v.z = fm[gpb + 2 * HW_ + sp];
            v.w = fm[gpb + 3 * HW_ + sp];
            sh4[p] = v;
        }
    }
    __syncthreads();

    const float4* __restrict__ rois4 = reinterpret_cast<const float4*>(rois) + n * R_;
    const size_t obase = ((size_t)n * R_ * C_ + c0) * PP_;

    for (int it = wv; it < NIT; it += WVS_) {
        const int t  = (it << 6) | lane;                 // 0 .. 12543
        const int ri = (int)((unsigned)t / 49u);         // roi 0..255 (magic mul)
        const int px = t - ri * 49;                      // pixel 0..48
        const int pi = (int)((unsigned)px / 7u);
        const int pj = px - pi * 7;

        const float4 roi = rois4[ri];
        const float y1 = roi.x * 0.0625f;
        const float x1 = roi.y * 0.0625f;
        const float y2 = (roi.x + roi.z) * 0.0625f;
        const float x2 = (roi.y + roi.w) * 0.0625f;
        const float sy = (y2 - y1) * (1.0f / 13.0f);
        const float sx = (x2 - x1) * (1.0f / 13.0f);

        const float py0 = y1 + sy * (float)(2 * pi);
        const float py1 = y1 + sy * (float)(2 * pi + 1);
        const float qx0 = x1 + sx * (float)(2 * pj);
        const float qx1 = x1 + sx * (float)(2 * pj + 1);

        int iy0; float wyA[2], wyB[3];
        axis_w(py0, py1, H_, iy0, wyA, wyB);
        int ix0; float wxA[2], wxB[3];
        axis_w(qx0, qx1, W_, ix0, wxA, wxB);
        const int gb = iy0 * W_ + ix0;        // <= 2499; reads reach <= 2601

        // 9 x ds_read_b128: the 3x3 window for all 4 channels at once.
        const float4* __restrict__ G = sh4 + gb;
        const float4 v00 = G[0],       v01 = G[1],          v02 = G[2];
        const float4 v10 = G[W_],      v11 = G[W_ + 1],     v12 = G[W_ + 2];
        const float4 v20 = G[2 * W_],  v21 = G[2 * W_ + 1], v22 = G[2 * W_ + 2];

        float r0, r1, r2, r3;
        // Pruned bilinear+max reduce per channel (25 VALU each); component
        // extraction is register naming, not work.
#define REDUCE_CH(CMP, RES) do {                                               \
        const float tA0 = fmaf(wyA[1], v10.CMP, wyA[0] * v00.CMP);             \
        const float tA1 = fmaf(wyA[1], v11.CMP, wyA[0] * v01.CMP);             \
        const float tA2 = fmaf(wyA[1], v12.CMP, wyA[0] * v02.CMP);             \
        const float tB0 = fmaf(wyB[2], v20.CMP, fmaf(wyB[1], v10.CMP, wyB[0] * v00.CMP)); \
        const float tB1 = fmaf(wyB[2], v21.CMP, fmaf(wyB[1], v11.CMP, wyB[0] * v01.CMP)); \
        const float tB2 = fmaf(wyB[2], v22.CMP, fmaf(wyB[1], v12.CMP, wyB[0] * v02.CMP)); \
        const float s00 = fmaf(wxA[1], tA1, wxA[0] * tA0);                     \
        const float s01 = fmaf(wxB[2], tA2, fmaf(wxB[1], tA1, wxB[0] * tA0));  \
        const float s10 = fmaf(wxA[1], tB1, wxA[0] * tB0);                     \
        const float s11 = fmaf(wxB[2], tB2, fmaf(wxB[1], tB1, wxB[0] * tB0));  \
        RES = fmaxf(fmaxf(s00, s01), fmaxf(s10, s11));                         \
    } while (0)
        REDUCE_CH(x, r0);
        REDUCE_CH(y, r1);
        REDUCE_CH(z, r2);
        REDUCE_CH(w, r3);
#undef REDUCE_CH

        float* __restrict__ po = out + obase + (size_t)ri * C_ * PP_ + px;
        po[0]       = r0;
        po[PP_]     = r1;
        po[2 * PP_] = r2;
        po[3 * PP_] = r3;
    }
}

extern "C" void kernel_launch(void* const* d_in, const int* in_sizes, int n_in,
                              void* d_out, int out_size, void* d_ws, size_t ws_size,
                              hipStream_t stream) {
    const float* rois = (const float*)d_in[0];        // [4,256,4]
    const float* fm   = (const float*)d_in[1];        // [4,1024,50,50]
    float* out        = (float*)d_out;                // [4,256,1024,7,7]

    const int blocks = N_ * (C_ / CHB_);              // 4 * 256 = 1024
    roipool_kernel<<<blocks, 512, 0, stream>>>(rois, fm, out);
}